// Round 20
// baseline (56.735 us; speedup 1.0000x reference)
//
#include <hip/hip_runtime.h>

// Involution1d fused v13 = R19 single-dispatch: weight conversion folded in.
// B=16, CH=256, DIM=4096, G=16, K=7, PAD=3, hid=64, K*G=112.
// TLC=32, 256-thread 4-wave blocks, LDS 28.5 KiB -> 5 blocks/CU.
// x staged K-MAJOR (xkt[col][ch], b64 writes / b128 frag reads);
// h transposed (hst[col][o], b64 writes / b128 frag reads);
// involution x-taps from global f32 (L2-hot via XCD-chunked swizzle).
// Weights read as f32 (L2-resident) + cvt_pkrtz in-kernel: no setup pass.
#define BB   16
#define CHN  256
#define DIMN 4096
#define KK   7
#define HID  64
#define KGN  112
#define TLC  32        // columns per tile
#define XKS  132       // xkt col stride in dw
#define HTS  33        // hst col stride in dw
#define KSTD 36        // ks row stride in dw (mult of 4 -> aligned uint4)
#define BN_EPS 1e-5f

typedef __fp16 half2_t __attribute__((ext_vector_type(2)));
typedef __fp16 half8   __attribute__((ext_vector_type(8)));
typedef float  f32x4   __attribute__((ext_vector_type(4)));

union U32H2 { unsigned int u; half2_t h; };
union U32H8 { unsigned int u[4]; half8 h; };

static __device__ __forceinline__ unsigned int packf(float a, float b) {
    U32H2 t; t.h = __builtin_amdgcn_cvt_pkrtz(a, b); return t.u;
}
static __device__ __forceinline__ half2_t ash2(unsigned int u) { U32H2 t; t.u = u; return t.h; }

// Build an f16 A-fragment from 8 consecutive f32 weights (L2-resident).
static __device__ __forceinline__ half8 wfrag(const float* __restrict__ wp) {
    float4 a = *(const float4*)wp;
    float4 b = *(const float4*)(wp + 4);
    U32H8 u;
    u.u[0] = packf(a.x, a.y);
    u.u[1] = packf(a.z, a.w);
    u.u[2] = packf(b.x, b.y);
    u.u[3] = packf(b.z, b.w);
    return u.h;
}

// LDS-only barrier: drains lgkmcnt but NOT vmcnt (validated R15-R19).
static __device__ __forceinline__ void bar_lds() {
    asm volatile("s_waitcnt lgkmcnt(0)" ::: "memory");
    __builtin_amdgcn_s_barrier();
    __builtin_amdgcn_sched_barrier(0);
}

// ---------------------------------------------------------------------------
// kern extraction from row-pair-packed uint4 quads; OFF = g&1.
template <int OFF>
static __device__ __forceinline__ void extract_kv(const uint4 q[4], float kv[KK][4]) {
#pragma unroll
    for (int k = 0; k < KK; ++k) {
        const int kk = k + OFF;
        const int i  = kk >> 1;
        const int h  = kk & 1;
#pragma unroll
        for (int j = 0; j < 4; ++j) {
            unsigned int u = (&q[i].x)[j];
            half2_t hh = ash2(u);
            kv[k][j] = h ? (float)hh[1] : (float)hh[0];
        }
    }
}

// ---------------------------------------------------------------------------
// Fused kernel.  Block = (b, 32-col tile), 4 waves, 5 blocks/CU.
// xkt[col][ch]: dw = col*132 + ((ch>>1) ^ ((col&7)<<4))   (f16 pairs over ch)
// hst[col][o] : dw = col*33  + (o>>1)                     (f16 pairs over o)
// Phase 1: wave w owns o-frag w, 2 col-frags.  Phase 2: rf in {w, w+4 (w<3)}.
// Involution: wave w owns g {4w..4w+3}; lane -> col quad (l&7), ch (l>>3);
// x taps read from GLOBAL f32 (L2-hot).
// Fragment maps (16x16x32): A[m][k]: m=lane&15, k=8*(lane>>4)+j;
// B[k][n]: n=lane&15; D[m][n]: n=lane&15, m=4*(lane>>4)+reg.
__global__ __launch_bounds__(256, 5) void fused_k(
    const float* __restrict__ x,
    const float* __restrict__ w1,
    const float* __restrict__ b1,
    const float* __restrict__ bn_gamma, const float* __restrict__ bn_beta,
    const float* __restrict__ bn_mean,  const float* __restrict__ bn_var,
    const float* __restrict__ w2,
    const float* __restrict__ b2,
    float* __restrict__ out) {
    __shared__ unsigned int xkt[TLC * XKS];   // 16896 B
    __shared__ unsigned int hst[TLC * HTS];   // 4224 B
    __shared__ unsigned int ks[56 * KSTD];    // 8064 B   (total 28.5 KiB)

    const unsigned short* xkt16 = (const unsigned short*)xkt;
    const unsigned short* hst16 = (const unsigned short*)hst;

    const int t    = threadIdx.x;          // 0..255
    const int lane = t & 63;
    const int w    = t >> 6;               // wave 0..3
    const int lr   = t & 15;
    const int lg   = (t >> 4) & 3;

    // XCD-chunked swizzle (2048 % 8 == 0 -> bijective); neighbor tiles share
    // an XCD's L2 -> inv's global x re-read is L2-hot.
    const int L  = (blockIdx.x & 7) * 256 + (blockIdx.x >> 3);
    const int b  = L >> 7;                 // 128 tiles per batch
    const int l0 = (L & 127) * TLC;

    // ---- Stage x -> xkt (k-major): 32 scalar global loads, 8 b64 writes ----
    {
        const int col = t & 31;
        const int chq = t >> 5;            // 0..7
        const int xsw = (col & 7) << 4;
        const float* xg = x + (size_t)b * CHN * DIMN + l0 + col;
#pragma unroll
        for (int i = 0; i < 8; ++i) {
            const int ch0 = 4 * chq + 32 * i;
            float f0 = xg[(size_t)(ch0 + 0) * DIMN];
            float f1 = xg[(size_t)(ch0 + 1) * DIMN];
            float f2 = xg[(size_t)(ch0 + 2) * DIMN];
            float f3 = xg[(size_t)(ch0 + 3) * DIMN];
            uint2 u;
            u.x = packf(f0, f1);
            u.y = packf(f2, f3);
            *(uint2*)&xkt[col * XKS + (((ch0 >> 1)) ^ xsw)] = u;
        }
    }
    bar_lds();

    // ---- Phase 1: h = w1 . x  (wave w: o-frag w, 2 col-frags, 8 K-steps) ----
    f32x4 acc[2];
#pragma unroll
    for (int cf = 0; cf < 2; ++cf) acc[cf] = (f32x4){0.f, 0.f, 0.f, 0.f};

#pragma unroll
    for (int p = 0; p < 8; ++p) {
        half8 af = wfrag(w1 + (16 * w + lr) * CHN + 32 * p + 8 * lg);
#pragma unroll
        for (int cf = 0; cf < 2; ++cf) {
            const int col = 16 * cf + lr;
            const int dwo = col * XKS + ((16 * p + 4 * lg) ^ ((col & 7) << 4));
            half8 bf = *(const half8*)(xkt16 + 2 * dwo);   // 1x ds_read_b128
            acc[cf] = __builtin_amdgcn_mfma_f32_16x16x32_f16(af, bf, acc[cf], 0, 0, 0);
        }
    }

    // ---- bias+relu+BN (inline affine); h -> hst[col][o] (2x b64 writes) ----
    float b1v[4], scv[4], shv[4];
#pragma unroll
    for (int r = 0; r < 4; ++r) {
        const int o = 16 * w + 4 * lg + r;
        b1v[r] = b1[o];
        float s = bn_gamma[o] * rsqrtf(bn_var[o] + BN_EPS);
        scv[r] = s;
        shv[r] = bn_beta[o] - bn_mean[o] * s;
    }
#pragma unroll
    for (int cf = 0; cf < 2; ++cf) {
        const int col = 16 * cf + lr;
        float hv[4];
#pragma unroll
        for (int r = 0; r < 4; ++r)
            hv[r] = fmaxf(acc[cf][r] + b1v[r], 0.f) * scv[r] + shv[r];
        uint2 u;
        u.x = packf(hv[0], hv[1]);
        u.y = packf(hv[2], hv[3]);
        *(uint2*)&hst[col * HTS + 8 * w + 2 * lg] = u;
    }
    bar_lds();

    // ---- Phase 2: kern = w2 . h  (wave w: rf in {w, w+4}, 2 K-steps) ----
    const int nrf = (w < 3) ? 2 : 1;
    f32x4 acc2[2][2];
#pragma unroll
    for (int ri = 0; ri < 2; ++ri)
#pragma unroll
        for (int cf = 0; cf < 2; ++cf) acc2[ri][cf] = (f32x4){0.f, 0.f, 0.f, 0.f};

#pragma unroll
    for (int kx = 0; kx < 2; ++kx) {
        half8 bf[2];
#pragma unroll
        for (int cf = 0; cf < 2; ++cf) {
            const int col = 16 * cf + lr;
            bf[cf] = *(const half8*)(hst16 + 2 * (col * HTS + 16 * kx + 4 * lg));
        }
        for (int ri = 0; ri < nrf; ++ri) {
            const int rf = w + 4 * ri;
            half8 af = wfrag(w2 + (16 * rf + lr) * HID + 32 * kx + 8 * lg);
            acc2[ri][0] = __builtin_amdgcn_mfma_f32_16x16x32_f16(af, bf[0], acc2[ri][0], 0, 0, 0);
            acc2[ri][1] = __builtin_amdgcn_mfma_f32_16x16x32_f16(af, bf[1], acc2[ri][1], 0, 0, 0);
        }
    }

    // ---- bias + row-pair pack -> ks ----
    for (int ri = 0; ri < nrf; ++ri) {
        const int rf = w + 4 * ri;
#pragma unroll
        for (int cf = 0; cf < 2; ++cf) {
#pragma unroll
            for (int p2 = 0; p2 < 2; ++p2) {
                const int r0 = 16 * rf + 4 * lg + 2 * p2;
                float k0 = acc2[ri][cf][2 * p2 + 0] + b2[r0 + 0];
                float k1 = acc2[ri][cf][2 * p2 + 1] + b2[r0 + 1];
                ks[(r0 >> 1) * KSTD + 16 * cf + lr] = packf(k0, k1);
            }
        }
    }
    bar_lds();

    // ---- Involution: wave w -> groups {4w..4w+3}; x taps from GLOBAL f32 ----
    const int q4    = lane & 7;
    const int hi    = lane >> 3;           // 0..7
    const int cbase = 4 * q4;
    const int col0  = l0 + cbase;

#pragma unroll
    for (int gi = 0; gi < 4; ++gi) {
        const int g   = 4 * w + gi;        // parity = gi & 1 (4w even)
        const int rpb = (7 * g) >> 1;
        uint4 qq[4];
#pragma unroll
        for (int ii = 0; ii < 4; ++ii)
            qq[ii] = *(const uint4*)(ks + (rpb + ii) * KSTD + cbase);
        float kv[KK][4];
        if ((gi & 1) == 0) extract_kv<0>(qq, kv);
        else               extract_kv<1>(qq, kv);

#pragma unroll
        for (int i2 = 0; i2 < 2; ++i2) {
            const int ch = 16 * g + 8 * i2 + hi;
            const float* xrow = x + ((size_t)b * CHN + ch) * DIMN;
            float4 fa = *(const float4*)(xrow + (col0 > 0 ? col0 - 4 : 0));
            float4 fb = *(const float4*)(xrow + col0);
            float4 fc = *(const float4*)(xrow + (col0 + 4 < DIMN ? col0 + 4 : DIMN - 4));

            float xr[10] = { fa.y, fa.z, fa.w, fb.x, fb.y, fb.z, fb.w, fc.x, fc.y, fc.z };
            if (col0 == 0)        { xr[0] = 0.f; xr[1] = 0.f; xr[2] = 0.f; }
            if (col0 == DIMN - 4) { xr[7] = 0.f; xr[8] = 0.f; xr[9] = 0.f; }

            float o0 = 0.f, o1 = 0.f, o2 = 0.f, o3 = 0.f;
#pragma unroll
            for (int k = 0; k < KK; ++k) {
                o0 = fmaf(kv[k][0], xr[k + 0], o0);
                o1 = fmaf(kv[k][1], xr[k + 1], o1);
                o2 = fmaf(kv[k][2], xr[k + 2], o2);
                o3 = fmaf(kv[k][3], xr[k + 3], o3);
            }
            *(float4*)(out + ((size_t)b * CHN + ch) * DIMN + col0) =
                make_float4(o0, o1, o2, o3);
        }
    }
}

// ---------------------------------------------------------------------------
extern "C" void kernel_launch(void* const* d_in, const int* in_sizes, int n_in,
                              void* d_out, int out_size, void* d_ws, size_t ws_size,
                              hipStream_t stream) {
    (void)in_sizes; (void)n_in; (void)out_size; (void)d_ws; (void)ws_size;

    const float* x        = (const float*)d_in[0];
    const float* w1       = (const float*)d_in[1];
    const float* b1       = (const float*)d_in[2];
    const float* bn_gamma = (const float*)d_in[3];
    const float* bn_beta  = (const float*)d_in[4];
    const float* bn_mean  = (const float*)d_in[5];
    const float* bn_var   = (const float*)d_in[6];
    const float* w2       = (const float*)d_in[7];
    const float* b2       = (const float*)d_in[8];
    float*       out      = (float*)d_out;

    fused_k<<<BB * (DIMN / TLC), 256, 0, stream>>>(
        x, w1, b1, bn_gamma, bn_beta, bn_mean, bn_var, w2, b2, out);
}

// Round 21
// 50.830 us; speedup vs baseline: 1.1162x; 1.1162x over previous
//
#include <hip/hip_runtime.h>

// Involution1d fused v12 (R19 restored — best measured: 51.57 us total).
// B=16, CH=256, DIM=4096, G=16, K=7, PAD=3, hid=64, K*G=112.
// TLC=32, 256-thread 4-wave blocks, LDS 28.5 KiB -> 5 blocks/CU.
// x staged K-MAJOR (xkt[col][ch], b64 writes / b128 frag reads);
// h transposed (hst[col][o], b64 writes / b128 frag reads);
// involution x-taps from global f32 (L2-hot via XCD-chunked swizzle).
// ~55 LDS instrs/thread.  3 lgkm-only barriers.
#define BB   16
#define CHN  256
#define DIMN 4096
#define KK   7
#define HID  64
#define KGN  112
#define TLC  32        // columns per tile
#define XKS  132       // xkt col stride in dw
#define HTS  33        // hst col stride in dw
#define KSTD 36        // ks row stride in dw (mult of 4 -> aligned uint4)
#define BN_EPS 1e-5f

typedef __fp16 half2_t __attribute__((ext_vector_type(2)));
typedef __fp16 half8   __attribute__((ext_vector_type(8)));
typedef float  f32x4   __attribute__((ext_vector_type(4)));

union U32H2 { unsigned int u; half2_t h; };

static __device__ __forceinline__ unsigned int packf(float a, float b) {
    U32H2 t; t.h = __builtin_amdgcn_cvt_pkrtz(a, b); return t.u;
}
static __device__ __forceinline__ half2_t ash2(unsigned int u) { U32H2 t; t.u = u; return t.h; }

// LDS-only barrier: drains lgkmcnt but NOT vmcnt (validated R15-R19).
static __device__ __forceinline__ void bar_lds() {
    asm volatile("s_waitcnt lgkmcnt(0)" ::: "memory");
    __builtin_amdgcn_s_barrier();
    __builtin_amdgcn_sched_barrier(0);
}

// ---------------------------------------------------------------------------
__global__ __launch_bounds__(256) void setup_k(
    const float* __restrict__ w1, const float* __restrict__ w2,
    const float* __restrict__ bn_gamma, const float* __restrict__ bn_beta,
    const float* __restrict__ bn_mean,  const float* __restrict__ bn_var,
    __fp16* __restrict__ w1f, __fp16* __restrict__ w2f,
    float* __restrict__ scb, float* __restrict__ shb) {
    int t = blockIdx.x * 256 + threadIdx.x;   // grid covers 16384
    if (t < HID * CHN) w1f[t] = (__fp16)w1[t];
    if (t < KGN * HID) w2f[t] = (__fp16)w2[t];
    if (t < HID) {
        float s = bn_gamma[t] * rsqrtf(bn_var[t] + BN_EPS);
        scb[t] = s;
        shb[t] = bn_beta[t] - bn_mean[t] * s;
    }
}

// ---------------------------------------------------------------------------
// kern extraction from row-pair-packed uint4 quads; OFF = g&1.
template <int OFF>
static __device__ __forceinline__ void extract_kv(const uint4 q[4], float kv[KK][4]) {
#pragma unroll
    for (int k = 0; k < KK; ++k) {
        const int kk = k + OFF;
        const int i  = kk >> 1;
        const int h  = kk & 1;
#pragma unroll
        for (int j = 0; j < 4; ++j) {
            unsigned int u = (&q[i].x)[j];
            half2_t hh = ash2(u);
            kv[k][j] = h ? (float)hh[1] : (float)hh[0];
        }
    }
}

// ---------------------------------------------------------------------------
// Fused kernel.  Block = (b, 32-col tile), 4 waves, 5 blocks/CU.
// xkt[col][ch]: dw = col*132 + ((ch>>1) ^ ((col&7)<<4))   (f16 pairs over ch)
// hst[col][o] : dw = col*33  + (o>>1)                     (f16 pairs over o)
// Phase 1: wave w owns o-frag w, 2 col-frags.  Phase 2: rf in {w, w+4 (w<3)}.
// Involution: wave w owns g {4w..4w+3}; lane -> col quad (l&7), ch (l>>3);
// x taps read from GLOBAL f32 (L2-hot).
// Fragment maps (16x16x32): A[m][k]: m=lane&15, k=8*(lane>>4)+j;
// B[k][n]: n=lane&15; D[m][n]: n=lane&15, m=4*(lane>>4)+reg.
__global__ __launch_bounds__(256, 5) void fused_k(
    const float* __restrict__ x,
    const __fp16* __restrict__ w1f,
    const float* __restrict__ b1,
    const float* __restrict__ scb, const float* __restrict__ shb,
    const __fp16* __restrict__ w2f,
    const float* __restrict__ b2,
    float* __restrict__ out) {
    __shared__ unsigned int xkt[TLC * XKS];   // 16896 B
    __shared__ unsigned int hst[TLC * HTS];   // 4224 B
    __shared__ unsigned int ks[56 * KSTD];    // 8064 B   (total 28.5 KiB)

    const unsigned short* xkt16 = (const unsigned short*)xkt;
    const unsigned short* hst16 = (const unsigned short*)hst;

    const int t    = threadIdx.x;          // 0..255
    const int lane = t & 63;
    const int w    = t >> 6;               // wave 0..3
    const int lr   = t & 15;
    const int lg   = (t >> 4) & 3;

    // XCD-chunked swizzle (2048 % 8 == 0 -> bijective); neighbor tiles share
    // an XCD's L2 -> inv's global x re-read is L2-hot.
    const int L  = (blockIdx.x & 7) * 256 + (blockIdx.x >> 3);
    const int b  = L >> 7;                 // 128 tiles per batch
    const int l0 = (L & 127) * TLC;

    // ---- Stage x -> xkt (k-major): 32 scalar global loads, 8 b64 writes ----
    {
        const int col = t & 31;
        const int chq = t >> 5;            // 0..7
        const int xsw = (col & 7) << 4;
        const float* xg = x + (size_t)b * CHN * DIMN + l0 + col;
#pragma unroll
        for (int i = 0; i < 8; ++i) {
            const int ch0 = 4 * chq + 32 * i;
            float f0 = xg[(size_t)(ch0 + 0) * DIMN];
            float f1 = xg[(size_t)(ch0 + 1) * DIMN];
            float f2 = xg[(size_t)(ch0 + 2) * DIMN];
            float f3 = xg[(size_t)(ch0 + 3) * DIMN];
            uint2 u;
            u.x = packf(f0, f1);
            u.y = packf(f2, f3);
            *(uint2*)&xkt[col * XKS + (((ch0 >> 1)) ^ xsw)] = u;
        }
    }
    bar_lds();

    // ---- Phase 1: h = w1 . x  (wave w: o-frag w, 2 col-frags, 8 K-steps) ----
    f32x4 acc[2];
#pragma unroll
    for (int cf = 0; cf < 2; ++cf) acc[cf] = (f32x4){0.f, 0.f, 0.f, 0.f};

#pragma unroll
    for (int p = 0; p < 8; ++p) {
        half8 af = *(const half8*)(w1f + (16 * w + lr) * CHN + 32 * p + 8 * lg);
#pragma unroll
        for (int cf = 0; cf < 2; ++cf) {
            const int col = 16 * cf + lr;
            const int dwo = col * XKS + ((16 * p + 4 * lg) ^ ((col & 7) << 4));
            half8 bf = *(const half8*)(xkt16 + 2 * dwo);   // 1x ds_read_b128
            acc[cf] = __builtin_amdgcn_mfma_f32_16x16x32_f16(af, bf, acc[cf], 0, 0, 0);
        }
    }

    // ---- bias+relu+BN; h -> hst[col][o] (2x ds_write_b64, crosses waves) ----
#pragma unroll
    for (int cf = 0; cf < 2; ++cf) {
        const int col = 16 * cf + lr;
        float hv[4];
#pragma unroll
        for (int r = 0; r < 4; ++r) {
            const int o = 16 * w + 4 * lg + r;
            hv[r] = fmaxf(acc[cf][r] + b1[o], 0.f) * scb[o] + shb[o];
        }
        uint2 u;
        u.x = packf(hv[0], hv[1]);
        u.y = packf(hv[2], hv[3]);
        *(uint2*)&hst[col * HTS + 8 * w + 2 * lg] = u;
    }
    bar_lds();

    // ---- Phase 2: kern = w2 . h  (wave w: rf in {w, w+4}, 2 K-steps) ----
    const int nrf = (w < 3) ? 2 : 1;
    f32x4 acc2[2][2];
#pragma unroll
    for (int ri = 0; ri < 2; ++ri)
#pragma unroll
        for (int cf = 0; cf < 2; ++cf) acc2[ri][cf] = (f32x4){0.f, 0.f, 0.f, 0.f};

#pragma unroll
    for (int kx = 0; kx < 2; ++kx) {
        half8 bf[2];
#pragma unroll
        for (int cf = 0; cf < 2; ++cf) {
            const int col = 16 * cf + lr;
            bf[cf] = *(const half8*)(hst16 + 2 * (col * HTS + 16 * kx + 4 * lg));
        }
        for (int ri = 0; ri < nrf; ++ri) {
            const int rf = w + 4 * ri;
            half8 af = *(const half8*)(w2f + (16 * rf + lr) * HID + 32 * kx + 8 * lg);
            acc2[ri][0] = __builtin_amdgcn_mfma_f32_16x16x32_f16(af, bf[0], acc2[ri][0], 0, 0, 0);
            acc2[ri][1] = __builtin_amdgcn_mfma_f32_16x16x32_f16(af, bf[1], acc2[ri][1], 0, 0, 0);
        }
    }

    // ---- bias + row-pair pack -> ks ----
    for (int ri = 0; ri < nrf; ++ri) {
        const int rf = w + 4 * ri;
#pragma unroll
        for (int cf = 0; cf < 2; ++cf) {
#pragma unroll
            for (int p2 = 0; p2 < 2; ++p2) {
                const int r0 = 16 * rf + 4 * lg + 2 * p2;
                float k0 = acc2[ri][cf][2 * p2 + 0] + b2[r0 + 0];
                float k1 = acc2[ri][cf][2 * p2 + 1] + b2[r0 + 1];
                ks[(r0 >> 1) * KSTD + 16 * cf + lr] = packf(k0, k1);
            }
        }
    }
    bar_lds();

    // ---- Involution: wave w -> groups {4w..4w+3}; x taps from GLOBAL f32 ----
    const int q4    = lane & 7;
    const int hi    = lane >> 3;           // 0..7
    const int cbase = 4 * q4;
    const int col0  = l0 + cbase;

#pragma unroll
    for (int gi = 0; gi < 4; ++gi) {
        const int g   = 4 * w + gi;        // parity = gi & 1 (4w even)
        const int rpb = (7 * g) >> 1;
        uint4 qq[4];
#pragma unroll
        for (int ii = 0; ii < 4; ++ii)
            qq[ii] = *(const uint4*)(ks + (rpb + ii) * KSTD + cbase);
        float kv[KK][4];
        if ((gi & 1) == 0) extract_kv<0>(qq, kv);
        else               extract_kv<1>(qq, kv);

#pragma unroll
        for (int i2 = 0; i2 < 2; ++i2) {
            const int ch = 16 * g + 8 * i2 + hi;
            const float* xrow = x + ((size_t)b * CHN + ch) * DIMN;
            float4 fa = *(const float4*)(xrow + (col0 > 0 ? col0 - 4 : 0));
            float4 fb = *(const float4*)(xrow + col0);
            float4 fc = *(const float4*)(xrow + (col0 + 4 < DIMN ? col0 + 4 : DIMN - 4));

            float xr[10] = { fa.y, fa.z, fa.w, fb.x, fb.y, fb.z, fb.w, fc.x, fc.y, fc.z };
            if (col0 == 0)        { xr[0] = 0.f; xr[1] = 0.f; xr[2] = 0.f; }
            if (col0 == DIMN - 4) { xr[7] = 0.f; xr[8] = 0.f; xr[9] = 0.f; }

            float o0 = 0.f, o1 = 0.f, o2 = 0.f, o3 = 0.f;
#pragma unroll
            for (int k = 0; k < KK; ++k) {
                o0 = fmaf(kv[k][0], xr[k + 0], o0);
                o1 = fmaf(kv[k][1], xr[k + 1], o1);
                o2 = fmaf(kv[k][2], xr[k + 2], o2);
                o3 = fmaf(kv[k][3], xr[k + 3], o3);
            }
            *(float4*)(out + ((size_t)b * CHN + ch) * DIMN + col0) =
                make_float4(o0, o1, o2, o3);
        }
    }
}

// ---------------------------------------------------------------------------
extern "C" void kernel_launch(void* const* d_in, const int* in_sizes, int n_in,
                              void* d_out, int out_size, void* d_ws, size_t ws_size,
                              hipStream_t stream) {
    (void)in_sizes; (void)n_in; (void)out_size; (void)ws_size;

    const float* x        = (const float*)d_in[0];
    const float* w1       = (const float*)d_in[1];
    const float* b1       = (const float*)d_in[2];
    const float* bn_gamma = (const float*)d_in[3];
    const float* bn_beta  = (const float*)d_in[4];
    const float* bn_mean  = (const float*)d_in[5];
    const float* bn_var   = (const float*)d_in[6];
    const float* w2       = (const float*)d_in[7];
    const float* b2       = (const float*)d_in[8];
    float*       out      = (float*)d_out;

    __fp16* w1f = (__fp16*)d_ws;                 // 16384 f16
    __fp16* w2f = w1f + HID * CHN;               // 7168 f16
    float*  scb = (float*)(w2f + KGN * HID);     // 64
    float*  shb = scb + HID;                     // 64

    setup_k<<<(HID * CHN + 255) / 256, 256, 0, stream>>>(
        w1, w2, bn_gamma, bn_beta, bn_mean, bn_var, w1f, w2f, scb, shb);
    fused_k<<<BB * (DIMN / TLC), 256, 0, stream>>>(
        x, w1f, b1, scb, shb, w2f, b2, out);
}